// Round 5
// baseline (172.134 us; speedup 1.0000x reference)
//
#include <hip/hip_runtime.h>
#include <hip/hip_bf16.h>
#include <math.h>

// Problem constants (reference: B=32, P=256, D=64, T=4096, SCALE=1)
#define Bb 32
#define Pp 256
#define Dd 64
#define Tt 4096

typedef unsigned short ushort_t;
typedef __attribute__((ext_vector_type(8))) short bf16x8;   // 8 bf16 = 4 VGPRs
typedef __attribute__((ext_vector_type(4))) float f32x4;

// Partials: 64 per (b,p), packed float2(lm = M + log2(ss), u = vv/ss).
#define TRIP_BYTES ((size_t)Bb * Pp * 64 * 8)    // 4,194,304
#define A_BF_BYTES ((size_t)Bb * Pp * Dd * 2)    // 1,048,576 (each of hi/lo)
#define B_BF_BYTES ((size_t)Tt * Dd * 2)         //   524,288 (each of hi/lo)
#define CNT_BYTES  128
#define WS_NEED    (TRIP_BYTES + 2 * A_BF_BYTES + 2 * B_BF_BYTES + CNT_BYTES)

// Log2-domain logits (R14/R16-validated): one v_exp_f32 per exp.
#define C2 (-0.7213475204444817f)   // -0.5 * log2(e)

__device__ __forceinline__ float fexp2(float x) {
  float r; asm("v_exp_f32 %0, %1" : "=v"(r) : "v"(x)); return r;
}
__device__ __forceinline__ float flog2(float x) {
  float r; asm("v_log_f32 %0, %1" : "=v"(r) : "v"(x)); return r;
}
__device__ __forceinline__ float frcp(float x) {
  float r; asm("v_rcp_f32 %0, %1" : "=v"(r) : "v"(x)); return r;
}

// ---- DPP row-local shuffle on the VALU pipe (R13-proven ctrl codes).
template <int CTRL>
__device__ __forceinline__ float dppf(float x) {
  return __builtin_bit_cast(float,
      __builtin_amdgcn_update_dpp(0, __builtin_bit_cast(int, x), CTRL, 0xF, 0xF, true));
}

// R9-proven split-bf16 6-MFMA product (drops al*bl, ~2^-17 rel err)
__device__ __forceinline__ f32x4 mfma6(bf16x8 ah0, bf16x8 ah1, bf16x8 al0, bf16x8 al1,
                                       bf16x8 bh0, bf16x8 bh1, bf16x8 bl0, bf16x8 bl1) {
  f32x4 a = (f32x4)0.f;
  a = __builtin_amdgcn_mfma_f32_16x16x32_bf16(ah0, bh0, a, 0, 0, 0);
  a = __builtin_amdgcn_mfma_f32_16x16x32_bf16(ah1, bh1, a, 0, 0, 0);
  a = __builtin_amdgcn_mfma_f32_16x16x32_bf16(ah0, bl0, a, 0, 0, 0);
  a = __builtin_amdgcn_mfma_f32_16x16x32_bf16(al0, bh0, a, 0, 0, 0);
  a = __builtin_amdgcn_mfma_f32_16x16x32_bf16(ah1, bl1, a, 0, 0, 0);
  a = __builtin_amdgcn_mfma_f32_16x16x32_bf16(al1, bh1, a, 0, 0, 0);
  return a;
}

// =============== Phase 0: split-bf16 conversion of A and B ==================
// Also zeroes the per-b merge counters (runs before k_main every graph exec).
__global__ __launch_bounds__(256) void k_conv(const float* __restrict__ data,
                                              const float* __restrict__ Wt,
                                              ushort_t* __restrict__ Ah, ushort_t* __restrict__ Al,
                                              ushort_t* __restrict__ Bh, ushort_t* __restrict__ Bl,
                                              int* __restrict__ cnt) {
  const int i  = blockIdx.x * 256 + threadIdx.x;
  if (i < Bb) cnt[i] = 0;
  const int NA = Bb * Pp * Dd;    // 524288
  const float x = (i < NA) ? data[i] : Wt[i - NA];
  const __hip_bfloat16 h = __float2bfloat16(x);
  const float hf = __bfloat162float(h);
  const __hip_bfloat16 l = __float2bfloat16(x - hf);
  if (i < NA) { Ah[i] = *(const ushort_t*)&h; Al[i] = *(const ushort_t*)&l; }
  else        { const int j = i - NA;
                Bh[j] = *(const ushort_t*)&h; Bl[j] = *(const ushort_t*)&l; }
}

// ==================== Phase 1: fused prefix-softmax + last-block merge ======
// R17 post-mortem of R16: occupancy 16->33% yet k_main 42->49us -> NOT
// latency-bound; per-wave amortization (64 t/wave, 4-nt MFMA runs, A
// prefetch) beats waves/SIMD. Restore the R13 body (proven 42us, VGPR 80,
// zero scratch) with the proven op-reductions kept:
//  - log2-domain logits (one v_exp_f32 per exp),
//  - M-first softmax: butterfly the exact max BEFORE exps -> single exp per
//    column, no mm pass, no rescale (argmax term 2^0=1 -> ss>=1, NaN-safe),
//  - partials compressed to float2(lm = M + log2 ss, u = vv/ss): TRIP and
//    partial-store traffic halved; merge algebraically exact.
// k_merge is FUSED via the canonical last-block pattern: each block, after
// its stores, does syncthreads -> tid0 {threadfence; atomicAdd(cnt[b])};
// the 16th block of b merges b's 256 rows (4 waves x 64 rows). Device-scope
// fence+atomic per G16; result independent of block order; cnt re-zeroed by
// k_conv each graph execution.
__global__ __launch_bounds__(256, 2) void k_main(const ushort_t* __restrict__ Ah,
                                                 const ushort_t* __restrict__ Al,
                                                 const ushort_t* __restrict__ Bh,
                                                 const ushort_t* __restrict__ Bl,
                                                 const float* __restrict__ targets,
                                                 float2* __restrict__ trips,
                                                 int* __restrict__ cnt,
                                                 float* __restrict__ out) {
  const int tid  = threadIdx.x;
  const int wid  = tid >> 6;
  const int lane = tid & 63;
  const int quad = lane >> 4;
  const int l16  = lane & 15;
  const int b     = blockIdx.x >> 4;
  const int strip = blockIdx.x & 15;
  const int t0    = strip * 256;
  const int wstrip = strip * 4 + wid;           // 0..63 (this wave's t-subset id)

  // ---- B fragments for this wave's 64 t-columns: VGPR-resident for all sgs.
  bf16x8 vbh0[4], vbh1[4], vbl0[4], vbl1[4];
#pragma unroll
  for (int nt = 0; nt < 4; ++nt) {
    const size_t boff = (size_t)(t0 + wid * 64 + nt * 16 + l16) * Dd + quad * 8;
    vbh0[nt] = *(const bf16x8*)(Bh + boff);
    vbh1[nt] = *(const bf16x8*)(Bh + boff + 32);
    vbl0[nt] = *(const bf16x8*)(Bl + boff);
    vbl1[nt] = *(const bf16x8*)(Bl + boff + 32);
  }

  const ushort_t* arow_base = Ah + (size_t)b * Pp * Dd;
  const ushort_t* alow_base = Al + (size_t)b * Pp * Dd;
  const float* tgt          = targets + b * Pp;
  float2* __restrict__ trb  = trips + (size_t)b * Pp * 64;

  float R[4];                                   // per-column running prefix (log2)
#pragma unroll
  for (int nt = 0; nt < 4; ++nt) R[nt] = 0.f;

  // prologue: A fragments + targets for sg=0
  const size_t aoff0 = (size_t)l16 * Dd + quad * 8;
  bf16x8 ah0 = *(const bf16x8*)(arow_base + aoff0);
  bf16x8 ah1 = *(const bf16x8*)(arow_base + aoff0 + 32);
  bf16x8 al0 = *(const bf16x8*)(alow_base + aoff0);
  bf16x8 al1 = *(const bf16x8*)(alow_base + aoff0 + 32);
  float4 tq  = *(const float4*)(tgt + quad * 4);

#pragma unroll 1
  for (int sg = 0; sg < 16; ++sg) {
    // ---- prefetch next sg's A-frags (wraps at sg=15: harmless L1-hot reload)
    const int pn = ((sg + 1) & 15) * 16;
    const size_t an = (size_t)(pn + l16) * Dd + quad * 8;
    const bf16x8 nah0 = *(const bf16x8*)(arow_base + an);
    const bf16x8 nah1 = *(const bf16x8*)(arow_base + an + 32);
    const bf16x8 nal0 = *(const bf16x8*)(alow_base + an);
    const bf16x8 nal1 = *(const bf16x8*)(alow_base + an + 32);
    const float4 ntq  = *(const float4*)(tgt + pn + quad * 4);

    float cc[4][4], av[4][4];
#pragma unroll
    for (int nt = 0; nt < 4; ++nt) {
      const f32x4 a = mfma6(ah0, ah1, al0, al1,
                            vbh0[nt], vbh1[nt], vbl0[nt], vbl1[nt]);
      float sc0, sc1, sc2, sc3;
      { const float e = tq.x - a[0]; sc0 = C2 * e * e; }
      { const float e = tq.y - a[1]; sc1 = C2 * e * e; }
      { const float e = tq.z - a[2]; sc2 = C2 * e * e; }
      { const float e = tq.w - a[3]; sc3 = C2 * e * e; }

      // quad-exclusive prefix of column sums (R11-proven; cross-row -> DS)
      const float colsum = (sc0 + sc1) + (sc2 + sc3);
      const float x1 = __shfl_xor(colsum, 16, 64);
      const float x2 = __shfl_xor(colsum, 32, 64);
      const float x3 = __shfl_xor(x1, 32, 64);
      const float pre = (quad == 0) ? 0.f
                      : (quad == 1) ? x1
                      : (quad == 2) ? (x2 + x3)
                                    : (x1 + x2 + x3);
      const float base = R[nt] + pre;
      cc[nt][0] = base;
      cc[nt][1] = base + sc0;
      cc[nt][2] = cc[nt][1] + sc1;
      cc[nt][3] = cc[nt][2] + sc2;
      av[nt][0] = a[0]; av[nt][1] = a[1]; av[nt][2] = a[2]; av[nt][3] = a[3];
      R[nt] += ((colsum + x1) + (x2 + x3));     // inclusive through this sg
    }

    // ---- M-first softmax: exact max over 64 t (in-lane 4 + DPP butterfly)
    float M[4];
#pragma unroll
    for (int r = 0; r < 4; ++r)
      M[r] = fmaxf(fmaxf(cc[0][r], cc[1][r]), fmaxf(cc[2][r], cc[3][r]));
#pragma unroll
    for (int r = 0; r < 4; ++r) M[r] = fmaxf(M[r], dppf<0xB1>(M[r]));   // xor1
#pragma unroll
    for (int r = 0; r < 4; ++r) M[r] = fmaxf(M[r], dppf<0x4E>(M[r]));   // xor2
#pragma unroll
    for (int r = 0; r < 4; ++r) M[r] = fmaxf(M[r], dppf<0x141>(M[r]));  // cross-4
#pragma unroll
    for (int r = 0; r < 4; ++r) M[r] = fmaxf(M[r], dppf<0x140>(M[r]));  // cross-8

    // single exp2 per column against the exact max (argmax term == 1)
    float ss[4], vv[4];
#pragma unroll
    for (int r = 0; r < 4; ++r) {
      float s = 0.f, v = 0.f;
#pragma unroll
      for (int nt = 0; nt < 4; ++nt) {
        const float e = fexp2(cc[nt][r] - M[r]);
        s += e;
        v = fmaf(e, av[nt][r], v);
      }
      ss[r] = s; vv[r] = v;
    }

#pragma unroll
    for (int r = 0; r < 4; ++r) { ss[r] += dppf<0xB1>(ss[r]);  vv[r] += dppf<0xB1>(vv[r]); }
#pragma unroll
    for (int r = 0; r < 4; ++r) { ss[r] += dppf<0x4E>(ss[r]);  vv[r] += dppf<0x4E>(vv[r]); }
#pragma unroll
    for (int r = 0; r < 4; ++r) { ss[r] += dppf<0x141>(ss[r]); vv[r] += dppf<0x141>(vv[r]); }
#pragma unroll
    for (int r = 0; r < 4; ++r) { ss[r] += dppf<0x140>(ss[r]); vv[r] += dppf<0x140>(vv[r]); }

    if (l16 == 0) {
#pragma unroll
      for (int r = 0; r < 4; ++r) {
        const float lm = M[r] + flog2(ss[r]);   // ss >= 1 -> log2 safe
        const float u  = vv[r] * frcp(ss[r]);
        const int p = sg * 16 + quad * 4 + r;
        trb[p * 64 + wstrip] = make_float2(lm, u);
      }
    }

    ah0 = nah0; ah1 = nah1; al0 = nal0; al1 = nal1; tq = ntq;
  }

  // ==================== fused cross-strip merge (last block of this b) ======
  __shared__ int s_old;
  __syncthreads();
  if (tid == 0) {
    __threadfence();                            // release this block's stores
    s_old = atomicAdd(&cnt[b], 1);
  }
  __syncthreads();
  if (s_old == 15) {
    __threadfence();                            // acquire all blocks' stores
#pragma unroll 1
    for (int p = wid; p < Pp; p += 4) {
      const float2 e = trb[p * 64 + lane];
      float M2 = e.x;
#pragma unroll
      for (int off = 32; off; off >>= 1) M2 = fmaxf(M2, __shfl_xor(M2, off, 64));
      const float f = fexp2(e.x - M2);
      float S = f, V = f * e.y;
#pragma unroll
      for (int off = 32; off; off >>= 1) {
        S += __shfl_xor(S, off, 64);
        V += __shfl_xor(V, off, 64);
      }
      if (lane == 0) out[b * Pp + p] = V / S;
    }
  }
}

// ==================== standalone merge (fallback path only) =================
__global__ __launch_bounds__(256) void k_merge(const float2* __restrict__ ws,
                                               float* __restrict__ out) {
  const int gt   = blockIdx.x * 256 + threadIdx.x;
  const int bp   = gt >> 6;
  const int lane = gt & 63;
  const float2 e = ws[(size_t)bp * 64 + lane];
  float M = e.x;
#pragma unroll
  for (int off = 32; off; off >>= 1) M = fmaxf(M, __shfl_xor(M, off, 64));
  const float f = fexp2(e.x - M);
  float S = f, V = f * e.y;
#pragma unroll
  for (int off = 32; off; off >>= 1) {
    S += __shfl_xor(S, off, 64);
    V += __shfl_xor(V, off, 64);
  }
  if (lane == 0) out[bp] = V / S;
}

// ============== Fallback (tiny ws): fused R1 structure + merge ==============
__global__ __launch_bounds__(256) void k_scan_fused(const float* __restrict__ data,
                                                    const float* __restrict__ targets,
                                                    const float* __restrict__ task_pool,
                                                    float2* __restrict__ ws) {
  const int b     = blockIdx.x >> 4;
  const int wid   = threadIdx.x >> 6;
  const int lane  = threadIdx.x & 63;
  const int chunk = ((blockIdx.x & 15) << 2) | wid;
  const int t     = (chunk << 6) | lane;
  float w[Dd];
#pragma unroll
  for (int d = 0; d < Dd; d += 4) {
    const float4 r = *(const float4*)(task_pool + (size_t)t * Dd + d);
    w[d] = r.x; w[d + 1] = r.y; w[d + 2] = r.z; w[d + 3] = r.w;
  }
  const float* drow = data + (size_t)b * (Pp * Dd);
  const float* tgt  = targets + b * Pp;
  float2* wsb       = ws + (size_t)b * (Pp * 64);
  float c = 0.f;
  for (int p = 0; p < Pp; ++p) {
    float a0 = 0.f, a1 = 0.f, a2 = 0.f, a3 = 0.f;
    const float* r = drow + p * Dd;
#pragma unroll
    for (int d = 0; d < Dd; d += 4) {
      a0 = fmaf(r[d], w[d], a0);         a1 = fmaf(r[d + 1], w[d + 1], a1);
      a2 = fmaf(r[d + 2], w[d + 2], a2); a3 = fmaf(r[d + 3], w[d + 3], a3);
    }
    const float pred = (a0 + a1) + (a2 + a3);
    float m = c;
#pragma unroll
    for (int off = 32; off; off >>= 1) m = fmaxf(m, __shfl_xor(m, off, 64));
    const float e = fexp2(c - m);
    float s = e, v = e * pred;
#pragma unroll
    for (int off = 32; off; off >>= 1) {
      s += __shfl_xor(s, off, 64);
      v += __shfl_xor(v, off, 64);
    }
    if (lane == 0) wsb[p * 64 + chunk] = make_float2(m + flog2(s), v * frcp(s));
    const float err = tgt[p] - pred;
    c = fmaf(C2 * err, err, c);
  }
}

extern "C" void kernel_launch(void* const* d_in, const int* in_sizes, int n_in,
                              void* d_out, int out_size, void* d_ws, size_t ws_size,
                              hipStream_t stream) {
  const float* data      = (const float*)d_in[0];
  const float* targets   = (const float*)d_in[1];
  const float* task_pool = (const float*)d_in[2];
  float* out = (float*)d_out;

  if (ws_size >= WS_NEED) {
    float2*   trips = (float2*)d_ws;
    char*     cb    = (char*)d_ws + TRIP_BYTES;
    ushort_t* Ah    = (ushort_t*)cb;
    ushort_t* Al    = (ushort_t*)(cb + A_BF_BYTES);
    ushort_t* Bh    = (ushort_t*)(cb + 2 * A_BF_BYTES);
    ushort_t* Bl    = (ushort_t*)(cb + 2 * A_BF_BYTES + B_BF_BYTES);
    int*      cnt   = (int*)(cb + 2 * A_BF_BYTES + 2 * B_BF_BYTES);
    k_conv <<<dim3((Bb * Pp * Dd + Tt * Dd) / 256), dim3(256), 0, stream>>>(
        data, task_pool, Ah, Al, Bh, Bl, cnt);
    k_main <<<dim3(Bb * 16), dim3(256), 0, stream>>>(Ah, Al, Bh, Bl, targets,
                                                     trips, cnt, out);
  } else {
    float2* trips = (float2*)d_ws;   // 4.2 MB
    k_scan_fused<<<dim3(512), dim3(256), 0, stream>>>(data, targets, task_pool, trips);
    k_merge<<<dim3((Bb * Pp * 64) / 256), dim3(256), 0, stream>>>(trips, out);
  }
}

// Round 6
// 99.544 us; speedup vs baseline: 1.7292x; 1.7292x over previous
//
#include <hip/hip_runtime.h>
#include <hip/hip_bf16.h>
#include <math.h>

// Problem constants (reference: B=32, P=256, D=64, T=4096, SCALE=1)
#define Bb 32
#define Pp 256
#define Dd 64
#define Tt 4096

typedef unsigned short ushort_t;
typedef __attribute__((ext_vector_type(8))) short bf16x8;   // 8 bf16 = 4 VGPRs
typedef __attribute__((ext_vector_type(4))) float f32x4;

// Partials: 64 per (b,p), packed float2(lm = M + log2(ss), u = vv/ss).
#define TRIP_BYTES ((size_t)Bb * Pp * 64 * 8)    // 4,194,304
#define A_BF_BYTES ((size_t)Bb * Pp * Dd * 2)    // 1,048,576 (each of hi/lo)
#define B_BF_BYTES ((size_t)Tt * Dd * 2)         //   524,288 (each of hi/lo)
#define WS_NEED    (TRIP_BYTES + 2 * A_BF_BYTES + 2 * B_BF_BYTES)

// Log2-domain logits (R14/R16-validated): one v_exp_f32 per exp.
#define C2 (-0.7213475204444817f)   // -0.5 * log2(e)

__device__ __forceinline__ float fexp2(float x) {
  float r; asm("v_exp_f32 %0, %1" : "=v"(r) : "v"(x)); return r;
}
__device__ __forceinline__ float flog2(float x) {
  float r; asm("v_log_f32 %0, %1" : "=v"(r) : "v"(x)); return r;
}
__device__ __forceinline__ float frcp(float x) {
  float r; asm("v_rcp_f32 %0, %1" : "=v"(r) : "v"(x)); return r;
}

// ---- DPP row-local shuffle on the VALU pipe (R13-proven ctrl codes).
// quad_perm xor1 = 0xB1, quad_perm xor2 = 0x4E,
// row_half_mirror = 0x141 (cross-4 merge), row_mirror = 0x140 (cross-8).
template <int CTRL>
__device__ __forceinline__ float dppf(float x) {
  return __builtin_bit_cast(float,
      __builtin_amdgcn_update_dpp(0, __builtin_bit_cast(int, x), CTRL, 0xF, 0xF, true));
}

// R9-proven split-bf16 6-MFMA product (drops al*bl, ~2^-17 rel err)
__device__ __forceinline__ f32x4 mfma6(bf16x8 ah0, bf16x8 ah1, bf16x8 al0, bf16x8 al1,
                                       bf16x8 bh0, bf16x8 bh1, bf16x8 bl0, bf16x8 bl1) {
  f32x4 a = (f32x4)0.f;
  a = __builtin_amdgcn_mfma_f32_16x16x32_bf16(ah0, bh0, a, 0, 0, 0);
  a = __builtin_amdgcn_mfma_f32_16x16x32_bf16(ah1, bh1, a, 0, 0, 0);
  a = __builtin_amdgcn_mfma_f32_16x16x32_bf16(ah0, bl0, a, 0, 0, 0);
  a = __builtin_amdgcn_mfma_f32_16x16x32_bf16(al0, bh0, a, 0, 0, 0);
  a = __builtin_amdgcn_mfma_f32_16x16x32_bf16(ah1, bl1, a, 0, 0, 0);
  a = __builtin_amdgcn_mfma_f32_16x16x32_bf16(al1, bh1, a, 0, 0, 0);
  return a;
}

// =============== Phase 0: split-bf16 conversion of A and B ==================
__global__ __launch_bounds__(256) void k_conv(const float* __restrict__ data,
                                              const float* __restrict__ Wt,
                                              ushort_t* __restrict__ Ah, ushort_t* __restrict__ Al,
                                              ushort_t* __restrict__ Bh, ushort_t* __restrict__ Bl) {
  const int i  = blockIdx.x * 256 + threadIdx.x;
  const int NA = Bb * Pp * Dd;    // 524288
  const float x = (i < NA) ? data[i] : Wt[i - NA];
  const __hip_bfloat16 h = __float2bfloat16(x);
  const float hf = __bfloat162float(h);
  const __hip_bfloat16 l = __float2bfloat16(x - hf);
  if (i < NA) { Ah[i] = *(const ushort_t*)&h; Al[i] = *(const ushort_t*)&l; }
  else        { const int j = i - NA;
                Bh[j] = *(const ushort_t*)&h; Bl[j] = *(const ushort_t*)&l; }
}

// ==================== Phase 1: one-pass fused prefix-softmax ================
// R18: R17's fused last-block merge REVERTED (counters: 8.6% time-avg
// occupancy, 120us -> ~78us tail where 32 blocks (1.5% of machine) walked a
// serial cross-XCD load+shuffle chain per p-row. The separate k_merge does
// the same work with 2048-block parallelism in ~2us; the saved launch gap
// (~5us) never pays for a serial tail.)
// Body = R13 structure (proven 42us: 64 t/wave, 4-nt MFMA runs, A-prefetch,
// launch_bounds(256,2), VGPR ~80, zero scratch) + proven op-reductions:
//  - log2-domain logits (one v_exp_f32 per exp),
//  - M-first softmax: exact-max DPP butterfly BEFORE exps -> single exp per
//    column, no mm pass, no rescale (argmax term 2^0=1 -> ss>=1, NaN-safe),
//  - partials compressed to float2(lm = M + log2 ss, u = vv/ss): partial
//    traffic halved; merge algebraically exact.
__global__ __launch_bounds__(256, 2) void k_main(const ushort_t* __restrict__ Ah,
                                                 const ushort_t* __restrict__ Al,
                                                 const ushort_t* __restrict__ Bh,
                                                 const ushort_t* __restrict__ Bl,
                                                 const float* __restrict__ targets,
                                                 float2* __restrict__ trips) {
  const int tid  = threadIdx.x;
  const int wid  = tid >> 6;
  const int lane = tid & 63;
  const int quad = lane >> 4;
  const int l16  = lane & 15;
  const int b     = blockIdx.x >> 4;
  const int strip = blockIdx.x & 15;
  const int t0    = strip * 256;
  const int wstrip = strip * 4 + wid;           // 0..63 (this wave's t-subset id)

  // ---- B fragments for this wave's 64 t-columns: VGPR-resident for all sgs.
  bf16x8 vbh0[4], vbh1[4], vbl0[4], vbl1[4];
#pragma unroll
  for (int nt = 0; nt < 4; ++nt) {
    const size_t boff = (size_t)(t0 + wid * 64 + nt * 16 + l16) * Dd + quad * 8;
    vbh0[nt] = *(const bf16x8*)(Bh + boff);
    vbh1[nt] = *(const bf16x8*)(Bh + boff + 32);
    vbl0[nt] = *(const bf16x8*)(Bl + boff);
    vbl1[nt] = *(const bf16x8*)(Bl + boff + 32);
  }

  const ushort_t* arow_base = Ah + (size_t)b * Pp * Dd;
  const ushort_t* alow_base = Al + (size_t)b * Pp * Dd;
  const float* tgt          = targets + b * Pp;
  float2* __restrict__ trb  = trips + (size_t)b * Pp * 64;

  float R[4];                                   // per-column running prefix (log2)
#pragma unroll
  for (int nt = 0; nt < 4; ++nt) R[nt] = 0.f;

  // prologue: A fragments + targets for sg=0
  const size_t aoff0 = (size_t)l16 * Dd + quad * 8;
  bf16x8 ah0 = *(const bf16x8*)(arow_base + aoff0);
  bf16x8 ah1 = *(const bf16x8*)(arow_base + aoff0 + 32);
  bf16x8 al0 = *(const bf16x8*)(alow_base + aoff0);
  bf16x8 al1 = *(const bf16x8*)(alow_base + aoff0 + 32);
  float4 tq  = *(const float4*)(tgt + quad * 4);

#pragma unroll 1
  for (int sg = 0; sg < 16; ++sg) {
    // ---- prefetch next sg's A-frags (wraps at sg=15: harmless L1-hot reload)
    const int pn = ((sg + 1) & 15) * 16;
    const size_t an = (size_t)(pn + l16) * Dd + quad * 8;
    const bf16x8 nah0 = *(const bf16x8*)(arow_base + an);
    const bf16x8 nah1 = *(const bf16x8*)(arow_base + an + 32);
    const bf16x8 nal0 = *(const bf16x8*)(alow_base + an);
    const bf16x8 nal1 = *(const bf16x8*)(alow_base + an + 32);
    const float4 ntq  = *(const float4*)(tgt + pn + quad * 4);

    float cc[4][4], av[4][4];
#pragma unroll
    for (int nt = 0; nt < 4; ++nt) {
      const f32x4 a = mfma6(ah0, ah1, al0, al1,
                            vbh0[nt], vbh1[nt], vbl0[nt], vbl1[nt]);
      float sc0, sc1, sc2, sc3;
      { const float e = tq.x - a[0]; sc0 = C2 * e * e; }
      { const float e = tq.y - a[1]; sc1 = C2 * e * e; }
      { const float e = tq.z - a[2]; sc2 = C2 * e * e; }
      { const float e = tq.w - a[3]; sc3 = C2 * e * e; }

      // quad-exclusive prefix of column sums (R11-proven; cross-row -> DS)
      const float colsum = (sc0 + sc1) + (sc2 + sc3);
      const float x1 = __shfl_xor(colsum, 16, 64);
      const float x2 = __shfl_xor(colsum, 32, 64);
      const float x3 = __shfl_xor(x1, 32, 64);
      const float pre = (quad == 0) ? 0.f
                      : (quad == 1) ? x1
                      : (quad == 2) ? (x2 + x3)
                                    : (x1 + x2 + x3);
      const float base = R[nt] + pre;
      cc[nt][0] = base;
      cc[nt][1] = base + sc0;
      cc[nt][2] = cc[nt][1] + sc1;
      cc[nt][3] = cc[nt][2] + sc2;
      av[nt][0] = a[0]; av[nt][1] = a[1]; av[nt][2] = a[2]; av[nt][3] = a[3];
      R[nt] += ((colsum + x1) + (x2 + x3));     // inclusive through this sg
    }

    // ---- M-first softmax: exact max over 64 t (in-lane 4 + DPP butterfly)
    float M[4];
#pragma unroll
    for (int r = 0; r < 4; ++r)
      M[r] = fmaxf(fmaxf(cc[0][r], cc[1][r]), fmaxf(cc[2][r], cc[3][r]));
#pragma unroll
    for (int r = 0; r < 4; ++r) M[r] = fmaxf(M[r], dppf<0xB1>(M[r]));   // xor1
#pragma unroll
    for (int r = 0; r < 4; ++r) M[r] = fmaxf(M[r], dppf<0x4E>(M[r]));   // xor2
#pragma unroll
    for (int r = 0; r < 4; ++r) M[r] = fmaxf(M[r], dppf<0x141>(M[r]));  // cross-4
#pragma unroll
    for (int r = 0; r < 4; ++r) M[r] = fmaxf(M[r], dppf<0x140>(M[r]));  // cross-8

    // single exp2 per column against the exact max (argmax term == 1)
    float ss[4], vv[4];
#pragma unroll
    for (int r = 0; r < 4; ++r) {
      float s = 0.f, v = 0.f;
#pragma unroll
      for (int nt = 0; nt < 4; ++nt) {
        const float e = fexp2(cc[nt][r] - M[r]);
        s += e;
        v = fmaf(e, av[nt][r], v);
      }
      ss[r] = s; vv[r] = v;
    }

#pragma unroll
    for (int r = 0; r < 4; ++r) { ss[r] += dppf<0xB1>(ss[r]);  vv[r] += dppf<0xB1>(vv[r]); }
#pragma unroll
    for (int r = 0; r < 4; ++r) { ss[r] += dppf<0x4E>(ss[r]);  vv[r] += dppf<0x4E>(vv[r]); }
#pragma unroll
    for (int r = 0; r < 4; ++r) { ss[r] += dppf<0x141>(ss[r]); vv[r] += dppf<0x141>(vv[r]); }
#pragma unroll
    for (int r = 0; r < 4; ++r) { ss[r] += dppf<0x140>(ss[r]); vv[r] += dppf<0x140>(vv[r]); }

    if (l16 == 0) {
#pragma unroll
      for (int r = 0; r < 4; ++r) {
        const float lm = M[r] + flog2(ss[r]);   // ss >= 1 -> log2 safe
        const float u  = vv[r] * frcp(ss[r]);
        const int p = sg * 16 + quad * 4 + r;
        trb[p * 64 + wstrip] = make_float2(lm, u);
      }
    }

    ah0 = nah0; ah1 = nah1; al0 = nal0; al1 = nal1; tq = ntq;
  }
}

// ==================== Phase 2: cross-strip merge (separate, parallel) =======
// 2048-block-equivalent parallelism: one 64-lane wave per (b,p) row.
__global__ __launch_bounds__(256) void k_merge(const float2* __restrict__ ws,
                                               float* __restrict__ out) {
  const int gt   = blockIdx.x * 256 + threadIdx.x;
  const int bp   = gt >> 6;
  const int lane = gt & 63;
  const float2 e = ws[(size_t)bp * 64 + lane];
  float M = e.x;
#pragma unroll
  for (int off = 32; off; off >>= 1) M = fmaxf(M, __shfl_xor(M, off, 64));
  const float f = fexp2(e.x - M);
  float S = f, V = f * e.y;
#pragma unroll
  for (int off = 32; off; off >>= 1) {
    S += __shfl_xor(S, off, 64);
    V += __shfl_xor(V, off, 64);
  }
  if (lane == 0) out[bp] = V / S;
}

// ============== Fallback (tiny ws): fused R1 structure + merge ==============
__global__ __launch_bounds__(256) void k_scan_fused(const float* __restrict__ data,
                                                    const float* __restrict__ targets,
                                                    const float* __restrict__ task_pool,
                                                    float2* __restrict__ ws) {
  const int b     = blockIdx.x >> 4;
  const int wid   = threadIdx.x >> 6;
  const int lane  = threadIdx.x & 63;
  const int chunk = ((blockIdx.x & 15) << 2) | wid;
  const int t     = (chunk << 6) | lane;
  float w[Dd];
#pragma unroll
  for (int d = 0; d < Dd; d += 4) {
    const float4 r = *(const float4*)(task_pool + (size_t)t * Dd + d);
    w[d] = r.x; w[d + 1] = r.y; w[d + 2] = r.z; w[d + 3] = r.w;
  }
  const float* drow = data + (size_t)b * (Pp * Dd);
  const float* tgt  = targets + b * Pp;
  float2* wsb       = ws + (size_t)b * (Pp * 64);
  float c = 0.f;
  for (int p = 0; p < Pp; ++p) {
    float a0 = 0.f, a1 = 0.f, a2 = 0.f, a3 = 0.f;
    const float* r = drow + p * Dd;
#pragma unroll
    for (int d = 0; d < Dd; d += 4) {
      a0 = fmaf(r[d], w[d], a0);         a1 = fmaf(r[d + 1], w[d + 1], a1);
      a2 = fmaf(r[d + 2], w[d + 2], a2); a3 = fmaf(r[d + 3], w[d + 3], a3);
    }
    const float pred = (a0 + a1) + (a2 + a3);
    float m = c;
#pragma unroll
    for (int off = 32; off; off >>= 1) m = fmaxf(m, __shfl_xor(m, off, 64));
    const float e = fexp2(c - m);
    float s = e, v = e * pred;
#pragma unroll
    for (int off = 32; off; off >>= 1) {
      s += __shfl_xor(s, off, 64);
      v += __shfl_xor(v, off, 64);
    }
    if (lane == 0) wsb[p * 64 + chunk] = make_float2(m + flog2(s), v * frcp(s));
    const float err = tgt[p] - pred;
    c = fmaf(C2 * err, err, c);
  }
}

extern "C" void kernel_launch(void* const* d_in, const int* in_sizes, int n_in,
                              void* d_out, int out_size, void* d_ws, size_t ws_size,
                              hipStream_t stream) {
  const float* data      = (const float*)d_in[0];
  const float* targets   = (const float*)d_in[1];
  const float* task_pool = (const float*)d_in[2];
  float* out = (float*)d_out;

  if (ws_size >= WS_NEED) {
    float2*   trips = (float2*)d_ws;
    char*     cb    = (char*)d_ws + TRIP_BYTES;
    ushort_t* Ah    = (ushort_t*)cb;
    ushort_t* Al    = (ushort_t*)(cb + A_BF_BYTES);
    ushort_t* Bh    = (ushort_t*)(cb + 2 * A_BF_BYTES);
    ushort_t* Bl    = (ushort_t*)(cb + 2 * A_BF_BYTES + B_BF_BYTES);
    k_conv <<<dim3((Bb * Pp * Dd + Tt * Dd) / 256), dim3(256), 0, stream>>>(
        data, task_pool, Ah, Al, Bh, Bl);
    k_main <<<dim3(Bb * 16), dim3(256), 0, stream>>>(Ah, Al, Bh, Bl, targets, trips);
    k_merge<<<dim3((Bb * Pp * 64) / 256), dim3(256), 0, stream>>>(trips, out);
  } else {
    float2* trips = (float2*)d_ws;   // 4.2 MB
    k_scan_fused<<<dim3(512), dim3(256), 0, stream>>>(data, targets, task_pool, trips);
    k_merge<<<dim3((Bb * Pp * 64) / 256), dim3(256), 0, stream>>>(trips, out);
  }
}